// Round 14
// baseline (368.151 us; speedup 1.0000x reference)
//
#include <hip/hip_runtime.h>
#include <hip/hip_bf16.h>
#include <math.h>

#define NTOK 65536
#define DIN 256
#define DOUT 256
#define HID 512
#define NEXP 8
#define NBAND 4
#define RANK 8
#define CAP 10240
#define NTILE 64
#define TILES_PER_E (CAP / NTILE)  // 160
#define TIEMAX 7000

// packed bf16 weight region (ushort elements), offsets in elements
#define W1CAT_PER_E (34 * 9 * 512)            // 156672
#define B1CAT_OFF   (NEXP * W1CAT_PER_E)      // 1253376
#define B1CAT_PER_E (32 * 512)                // 16384
#define W2CAT_OFF   (B1CAT_OFF + NEXP * B1CAT_PER_E)  // 1384448
#define W2CAT_PER_E (18 * 16 * 512)           // 147456
#define B2CAT_OFF   (W2CAT_OFF + NEXP * W2CAT_PER_E)  // 2564096
#define B2CAT_PER_E (16 * 512)                // 8192
#define PK_TOTAL    (B2CAT_OFF + NEXP * B2CAT_PER_E)  // 2629632 = 2568*1024
#define PK_F32_OFF  1200000                   // f32-word offset of packed region in ws

typedef short s16x8 __attribute__((ext_vector_type(8)));
typedef float f32x4 __attribute__((ext_vector_type(4)));

__device__ __forceinline__ unsigned key_of(float f) {
    unsigned u = __float_as_uint(f);
    return (u & 0x80000000u) ? ~u : (u | 0x80000000u);
}
// fast tanh-gelu: tanh(z) = 1 - 2/(e^{2z}+1)  ->  gelu(v) = v*(1 - rcp(e^{2z}+1))
__device__ __forceinline__ float gelu_fast(float v) {
    const float c = 0.7978845608028654f;
    float z = c * (v + 0.044715f * v * v * v);
    float e = __expf(2.0f * z);              // inf for large z -> rcp -> 0 (ok)
    return v * (1.0f - __builtin_amdgcn_rcpf(e + 1.0f));
}
__device__ __forceinline__ ushort f2bf(float f) {  // RNE f32->bf16
    unsigned u = __float_as_uint(f);
    return (ushort)((u + 0x7FFFu + ((u >> 16) & 1u)) >> 16);
}

// ---------------- gating GEMV + weff-fold + y-zero + 16-bit key histogram ---
__global__ __launch_bounds__(256) void k_logits(const float* __restrict__ x,
                                                const float* __restrict__ Wdct,
                                                const float* __restrict__ Wgate,
                                                float* __restrict__ logitsT,
                                                float* __restrict__ partials,
                                                float* __restrict__ y,
                                                unsigned* __restrict__ hist16) {
    __shared__ float wefft[8][257];   // [e][d], padded row
    __shared__ float pr[4][8];
    int tid = threadIdx.x, w = tid >> 6, lane = tid & 63;

    // fold weff: thread d computes row d (same accumulation order as before)
    {
        int d = tid;
        float acc[8];
#pragma unroll
        for (int e = 0; e < 8; ++e) acc[e] = Wgate[d * 8 + e];
        for (int f = 0; f < 64; ++f) {
            float wv = Wdct[d * 64 + f];
#pragma unroll
            for (int e = 0; e < 8; ++e) acc[e] += wv * Wgate[(256 + f) * 8 + e];
        }
#pragma unroll
        for (int e = 0; e < 8; ++e) wefft[e][d] = acc[e];
    }

    // zero this block's 64 output rows
    {
        float4 z = {0.f, 0.f, 0.f, 0.f};
        float4* yp = (float4*)(y + (size_t)blockIdx.x * 64 * DOUT);
        for (int i = tid; i < 4096; i += 256) yp[i] = z;
    }
    __syncthreads();

    float wje[4][8];
#pragma unroll
    for (int j = 0; j < 4; ++j)
#pragma unroll
        for (int e = 0; e < 8; ++e) wje[j][e] = wefft[e][lane * 4 + j];

    int wid = blockIdx.x * 4 + w;       // 0..4095
    int nbase = wid * 16;
    float es = 0.f;
    for (int t = 0; t < 16; ++t) {
        int n = nbase + t;
        float4 v = *(const float4*)(x + (size_t)n * DIN + lane * 4);
        float acc[8];
#pragma unroll
        for (int e = 0; e < 8; ++e) acc[e] = 0.f;
#pragma unroll
        for (int j = 0; j < 4; ++j) {
            float vj = (j == 0) ? v.x : (j == 1) ? v.y : (j == 2) ? v.z : v.w;
#pragma unroll
            for (int e = 0; e < 8; ++e) acc[e] += vj * wje[j][e];
        }
#pragma unroll
        for (int off = 1; off < 64; off <<= 1) {
#pragma unroll
            for (int e = 0; e < 8; ++e) acc[e] += __shfl_xor(acc[e], off);
        }
        float out = acc[0];
#pragma unroll
        for (int e = 1; e < 8; ++e) if (lane == e) out = acc[e];
        if (lane < 8) {
            logitsT[(size_t)lane * NTOK + n] = out;
            es += expf(out);
            atomicAdd(&hist16[((size_t)lane << 16) + (key_of(out) >> 16)], 1u);
        }
    }
    if (lane < 8) pr[w][lane] = es;
    __syncthreads();
    if (tid < 8) partials[(size_t)tid * 1024 + blockIdx.x] =
        pr[0][tid] + pr[1][tid] + pr[2][tid] + pr[3][tid];
}

// ---------------- fused: top-CAP select (blocks 0..7) || weight pack --------
// Selection: exact 16-bit-bin threshold from hist16 (one suffix scan) + one
// select pass; ties within the threshold bin ranked by full 32-bit key +
// lowest-index (set-identical to the former 4-pass radix).
__global__ __launch_bounds__(1024) void k_misc(const float* __restrict__ logitsT,
                                               const float* __restrict__ partials,
                                               float* __restrict__ colsum,
                                               int* __restrict__ idxbuf,
                                               const unsigned* __restrict__ hist16,
                                               int* __restrict__ tbuf,
                                               const float* __restrict__ W1,
                                               const float* __restrict__ A1,
                                               const float* __restrict__ B1,
                                               const float* __restrict__ W2,
                                               const float* __restrict__ A2,
                                               const float* __restrict__ B2,
                                               ushort* __restrict__ pk) {
    if (blockIdx.x >= 8) {
        // ---- weight packing branch ----
        int id = (blockIdx.x - 8) * 1024 + threadIdx.x;
        if (id >= PK_TOTAL) return;
        float val;
        if (id < B1CAT_OFF) {
            int e = id / W1CAT_PER_E, rem = id % W1CAT_PER_E;
            int t = rem / (9 * 512); rem %= 9 * 512;
            int s = rem / 512; int q = rem & 511;
            int l = q >> 3, j = q & 7;
            int k = s * 32 + ((l >> 4) << 3) + j;
            int col = t * 16 + (l & 15);
            if (k > 256) val = 0.f;
            else if (col < 512) val = W1[((size_t)e * 257 + k) * 512 + col];
            else {
                int cu = col - 512;
                val = A1[(((size_t)e * NBAND + (cu >> 3)) * 257 + k) * RANK + (cu & 7)];
            }
        } else if (id < W2CAT_OFF) {
            int id2 = id - B1CAT_OFF;
            int e = id2 / B1CAT_PER_E, rem = id2 % B1CAT_PER_E;
            int t = rem / 512; int q = rem & 511;
            int l = q >> 3, j = q & 7;
            int k32 = ((l >> 4) << 3) + j;
            int col = t * 16 + (l & 15);
            val = 2.0f * B1[(((size_t)e * NBAND + (k32 >> 3)) * RANK + (k32 & 7)) * 512 + col];
        } else if (id < B2CAT_OFF) {
            int id2 = id - W2CAT_OFF;
            int e = id2 / W2CAT_PER_E, rem = id2 % W2CAT_PER_E;
            int t = rem / (16 * 512); rem %= 16 * 512;
            int s = rem / 512; int q = rem & 511;
            int l = q >> 3, j = q & 7;
            int k = s * 32 + ((l >> 4) << 3) + j;
            int col = t * 16 + (l & 15);
            if (col < 256) val = W2[((size_t)e * 512 + k) * 256 + col];
            else {
                int cv = col - 256;
                val = A2[(((size_t)e * NBAND + (cv >> 3)) * 512 + k) * RANK + (cv & 7)];
            }
        } else {
            int id2 = id - B2CAT_OFF;
            int e = id2 / B2CAT_PER_E, rem = id2 % B2CAT_PER_E;
            int t = rem / 512; int q = rem & 511;
            int l = q >> 3, j = q & 7;
            int k32 = ((l >> 4) << 3) + j;
            int col = t * 16 + (l & 15);
            val = 2.0f * B2[(((size_t)e * NBAND + (k32 >> 3)) * RANK + (k32 & 7)) * 256 + col];
        }
        pk[id] = f2bf(val);
        return;
    }
    // ---- top-CAP selection branch (one block per expert) ----
    __shared__ unsigned chunk[1024];
    __shared__ float ssum[16];
    __shared__ unsigned sval[2];   // threshold bin B, rem
    __shared__ unsigned scnt, stcnt;
    int e = blockIdx.x, tid = threadIdx.x, w = tid >> 6, lane = tid & 63;
    const float* lp = logitsT + (size_t)e * NTOK;
    const unsigned* h = hist16 + ((size_t)e << 16);
    int* tb = tbuf + (size_t)e * TIEMAX;

    // colsum finalize
    {
        float s = partials[(size_t)e * 1024 + tid];
#pragma unroll
        for (int off = 32; off > 0; off >>= 1) s += __shfl_xor(s, off);
        if (lane == 0) ssum[w] = s;
        __syncthreads();
        if (tid == 0) {
            float t = 0.f;
#pragma unroll
            for (int i = 0; i < 16; ++i) t += ssum[i];
            colsum[e] = t;
        }
    }
    if (tid == 0) { scnt = 0; stcnt = 0; }

    // threshold: suffix-scan of 64K bins (each thread owns 64 bins)
    {
        unsigned csum = 0;
        for (int i = 0; i < 64; ++i) csum += h[tid * 64 + i];
        chunk[tid] = csum;
        __syncthreads();
        for (int off = 1; off < 1024; off <<= 1) {
            unsigned add = (tid + off < 1024) ? chunk[tid + off] : 0u;
            __syncthreads();
            chunk[tid] += add;
            __syncthreads();
        }
        unsigned above = (tid == 1023) ? 0u : chunk[tid + 1];
        unsigned s = above;
        for (int b = 63; b >= 0; --b) {
            unsigned prev = s;
            s += h[tid * 64 + b];
            if (s >= (unsigned)CAP && prev < (unsigned)CAP) {
                sval[0] = (unsigned)(tid * 64 + b);
                sval[1] = (unsigned)CAP - prev;
            }
        }
        __syncthreads();
    }
    unsigned B = sval[0], rem = sval[1];

    // single select pass
    for (int it = 0; it < 64; ++it) {
        int n = it * 1024 + tid;
        unsigned k16 = key_of(lp[n]) >> 16;
        if (k16 > B) {
            unsigned pos = atomicAdd(&scnt, 1u);
            idxbuf[e * CAP + pos] = n;
        } else if (k16 == B) {
            unsigned tp = atomicAdd(&stcnt, 1u);
            if (tp < TIEMAX) tb[tp] = n;
        }
    }
    __syncthreads();
    int m = (int)min(stcnt, (unsigned)TIEMAX), r = (int)rem, base = CAP - r;
    if (m == r) {
        for (int i = tid; i < m; i += 1024) idxbuf[e * CAP + base + i] = tb[i];
    } else {
        // rank ties by (full key desc, index asc); r best get slots
        for (int i = tid; i < m; i += 1024) {
            int my = tb[i];
            unsigned km = key_of(lp[my]);
            int rank = 0;
            for (int j = 0; j < m; ++j) {
                int oj = tb[j];
                unsigned kj = key_of(lp[oj]);
                rank += (kj > km) || (kj == km && oj < my);
            }
            if (rank < r) idxbuf[e * CAP + base + rank] = my;
        }
    }
}

// ---------------- fused expert MLP: block-cooperative LDS staging -----------
// r11 structure; launch_bounds min-waves 2 -> 3: force allocator under ~168
// VGPR so 3 blocks/CU fit (LDS 43KB allows exactly 3) -> 12 waves/CU.
__global__ __launch_bounds__(256, 3) void k_expert(
    const float* __restrict__ x, const int* __restrict__ band,
    const float* __restrict__ b1, const float* __restrict__ b2,
    const ushort* __restrict__ pk,
    const float* __restrict__ logitsT,
    const float* __restrict__ colsum, const int* __restrict__ idxbuf,
    float* __restrict__ y) {
    __shared__ ushort bW1[9216];        // 18 chunks x 512 (tiles 2p,2p+1 x 9 ksteps)
    __shared__ ushort bW2[9216];        // 18 chunks x 512 (t2 0..17, slice p)
    __shared__ ushort sc[4][640];       // per-wave transpose scratch
    __shared__ int s_tok[4][16];
    __shared__ int s_band[4][16];
    __shared__ float s_g[4][16];

    int tid = threadIdx.x, w = tid >> 6, lane = tid & 63;
    int bid = blockIdx.x;
    int e = bid & 7;            // XCD-pinned expert
    int tile = bid >> 3;        // 0..159

    if (lane < 16) {
        int n = idxbuf[e * CAP + tile * NTILE + w * 16 + lane];
        s_tok[w][lane] = n;
        s_band[w][lane] = band[n];
        s_g[w][lane] = expf(logitsT[(size_t)e * NTOK + n]) / colsum[e];
    }

    int l15 = lane & 15, lg = lane >> 4;
    ushort* scw = &sc[w][0];

    // ---- A-frags for layer 1 (K=288: 9 ksteps) ----
    s16x8 a1[9];
    {
        int mytok = s_tok[w][l15];
        const float* xrow = x + (size_t)mytok * DIN;
        int kg = lg << 3;
#pragma unroll
        for (int s = 0; s < 8; ++s) {
            float4 p = *(const float4*)&xrow[s * 32 + kg];
            float4 q = *(const float4*)&xrow[s * 32 + kg + 4];
            s16x8 a;
            a[0] = (short)f2bf(p.x); a[1] = (short)f2bf(p.y);
            a[2] = (short)f2bf(p.z); a[3] = (short)f2bf(p.w);
            a[4] = (short)f2bf(q.x); a[5] = (short)f2bf(q.y);
            a[6] = (short)f2bf(q.z); a[7] = (short)f2bf(q.w);
            a1[s] = a;
        }
        s16x8 a = (s16x8)(short)0;
        if (lane < 16) a[0] = (short)f2bf((float)s_band[w][l15] * 0.25f);
        a1[8] = a;
    }

    const ushort* w1base = pk + (size_t)e * W1CAT_PER_E;
    const ushort* b1base = pk + B1CAT_OFF + (size_t)e * B1CAT_PER_E;
    const ushort* w2base = pk + W2CAT_OFF + (size_t)e * W2CAT_PER_E;
    const ushort* b2base = pk + B2CAT_OFF + (size_t)e * B2CAT_PER_E;

    // ---- issue prologue stage loads (phase 0) into regs ----
    s16x8 stg[9];
    if (w < 2) {
        const ushort* s0 = w2base + (size_t)(w * 9) * 16 * 512 + lane * 8;
#pragma unroll
        for (int i = 0; i < 9; ++i)
            stg[i] = *(const s16x8*)(s0 + (size_t)i * 16 * 512);
    } else {
        const ushort* s0 = w1base + (size_t)(w - 2) * 9 * 512 + lane * 8;
#pragma unroll
        for (int i = 0; i < 9; ++i)
            stg[i] = *(const s16x8*)(s0 + i * 512);
    }

    // ---- LoRA1 u = xe @ A1cat (tiles 32,33, direct global), band-mask ----
    s16x8 ufrag;
    {
#pragma unroll
        for (int t = 32; t <= 33; ++t) {
            f32x4 acc = {0.f, 0.f, 0.f, 0.f};
#pragma unroll
            for (int s = 0; s < 9; ++s) {
                s16x8 b = *(const s16x8*)(w1base + ((size_t)t * 9 + s) * 512 + lane * 8);
                acc = __builtin_amdgcn_mfma_f32_16x16x32_bf16(a1[s], b, acc, 0, 0, 0);
            }
            int colbase = (t - 32) * 16 + l15;
#pragma unroll
            for (int r = 0; r < 4; ++r) {
                int row = lg * 4 + r;
                float v = ((colbase >> 3) == s_band[w][row]) ? acc[r] : 0.f;
                scw[row * 40 + colbase] = f2bf(v);
            }
        }
        ufrag = *(const s16x8*)&scw[l15 * 40 + lg * 8];
    }

    // ---- layer2 accumulators (bias-initialized), LoRA2 accumulators ----
    f32x4 oacc[16];
#pragma unroll
    for (int t2 = 0; t2 < 16; ++t2) {
        float bv = b2[(size_t)e * DOUT + t2 * 16 + l15];
        oacc[t2] = (f32x4){bv, bv, bv, bv};
    }
    f32x4 vacc[2];
    vacc[0] = (f32x4){0.f, 0.f, 0.f, 0.f};
    vacc[1] = (f32x4){0.f, 0.f, 0.f, 0.f};

    // ---- write prologue staged regs to the buffer, sync ----
    if (w < 2) {
#pragma unroll
        for (int i = 0; i < 9; ++i)
            *(s16x8*)(&bW2[(w * 9 + i) * 512] + lane * 8) = stg[i];
    } else {
#pragma unroll
        for (int i = 0; i < 9; ++i)
            *(s16x8*)(&bW1[((w - 2) * 9 + i) * 512] + lane * 8) = stg[i];
    }
    __syncthreads();

#pragma unroll 1
    for (int p = 0; p < 16; ++p) {
        // (a) issue next phase's global loads into regs (land during compute)
        s16x8 st2[9];
        if (p < 15) {
            int p1 = p + 1;
            if (w < 2) {
                const ushort* s0 = w2base + ((size_t)(w * 9) * 16 + p1) * 512 + lane * 8;
#pragma unroll
                for (int i = 0; i < 9; ++i)
                    st2[i] = *(const s16x8*)(s0 + (size_t)i * 16 * 512);
            } else {
                int t = p1 * 2 + (w - 2);
                const ushort* s0 = w1base + (size_t)t * 9 * 512 + lane * 8;
#pragma unroll
                for (int i = 0; i < 9; ++i)
                    st2[i] = *(const s16x8*)(s0 + i * 512);
            }
        }
        // (b) compute phase p from LDS
#pragma unroll
        for (int half = 0; half < 2; ++half) {
            int t = p * 2 + half;
            float bv = b1[(size_t)e * HID + t * 16 + l15];
            f32x4 acc = {bv, bv, bv, bv};
#pragma unroll
            for (int s = 0; s < 9; ++s) {
                s16x8 b = *(const s16x8*)(&bW1[(half * 9 + s) * 512] + lane * 8);
                acc = __builtin_amdgcn_mfma_f32_16x16x32_bf16(a1[s], b, acc, 0, 0, 0);
            }
            {
                s16x8 b = *(const s16x8*)(b1base + (size_t)t * 512 + lane * 8);
                acc = __builtin_amdgcn_mfma_f32_16x16x32_bf16(ufrag, b, acc, 0, 0, 0);
            }
#pragma unroll
            for (int r = 0; r < 4; ++r) {
                int row = lg * 4 + r;
                scw[row * 40 + half * 16 + l15] = f2bf(gelu_fast(acc[r]));
            }
        }
        s16x8 hfrag = *(const s16x8*)&scw[l15 * 40 + lg * 8];
#pragma unroll
        for (int t2 = 0; t2 < 16; ++t2) {
            s16x8 b = *(const s16x8*)(&bW2[t2 * 512] + lane * 8);
            oacc[t2] = __builtin_amdgcn_mfma_f32_16x16x32_bf16(hfrag, b, oacc[t2], 0, 0, 0);
        }
#pragma unroll
        for (int i = 0; i < 2; ++i) {
            s16x8 b = *(const s16x8*)(&bW2[(16 + i) * 512] + lane * 8);
            vacc[i] = __builtin_amdgcn_mfma_f32_16x16x32_bf16(hfrag, b, vacc[i], 0, 0, 0);
        }
        // (c) all waves done READING the buffer -> overwrite with next phase
        if (p < 15) {
            __syncthreads();
            if (w < 2) {
#pragma unroll
                for (int i = 0; i < 9; ++i)
                    *(s16x8*)(&bW2[(w * 9 + i) * 512] + lane * 8) = st2[i];
            } else {
#pragma unroll
                for (int i = 0; i < 9; ++i)
                    *(s16x8*)(&bW1[((w - 2) * 9 + i) * 512] + lane * 8) = st2[i];
            }
            __syncthreads();
        }
    }

    // ---- LoRA2: band-mask v, transpose -> vfrag, fold through B2cat ----
    s16x8 vfrag;
    {
#pragma unroll
        for (int i = 0; i < 2; ++i) {
            int colbase = i * 16 + l15;
#pragma unroll
            for (int r = 0; r < 4; ++r) {
                int row = lg * 4 + r;
                float v = ((colbase >> 3) == s_band[w][row]) ? vacc[i][r] : 0.f;
                scw[row * 40 + colbase] = f2bf(v);
            }
        }
        vfrag = *(const s16x8*)&scw[l15 * 40 + lg * 8];
    }

    float g4[4];
    int tok4[4];
#pragma unroll
    for (int r = 0; r < 4; ++r) {
        int row = lg * 4 + r;
        g4[r] = s_g[w][row];
        tok4[r] = s_tok[w][row];
    }
#pragma unroll
    for (int t2 = 0; t2 < 16; ++t2) {
        s16x8 b = *(const s16x8*)(b2base + (size_t)t2 * 512 + lane * 8);
        f32x4 acc = __builtin_amdgcn_mfma_f32_16x16x32_bf16(vfrag, b, oacc[t2], 0, 0, 0);
        int col = t2 * 16 + l15;
#pragma unroll
        for (int r = 0; r < 4; ++r) {
            atomicAdd(&y[(size_t)tok4[r] * DOUT + col], g4[r] * acc[r]);
        }
    }
}

extern "C" void kernel_launch(void* const* d_in, const int* in_sizes, int n_in,
                              void* d_out, int out_size, void* d_ws, size_t ws_size,
                              hipStream_t stream) {
    const float* x = (const float*)d_in[0];
    const int* band = (const int*)d_in[1];
    const float* Wdct = (const float*)d_in[2];
    const float* Wgate = (const float*)d_in[3];
    const float* W1 = (const float*)d_in[4];
    const float* b1 = (const float*)d_in[5];
    const float* A1 = (const float*)d_in[6];
    const float* B1 = (const float*)d_in[7];
    const float* W2 = (const float*)d_in[8];
    const float* b2 = (const float*)d_in[9];
    const float* A2 = (const float*)d_in[10];
    const float* B2 = (const float*)d_in[11];
    float* y = (float*)d_out;

    float* ws = (float*)d_ws;
    float* logitsT = ws;                          // 0 .. 524288
    float* partials = ws + 524288;                // 8192 (8 x 1024)
    float* colsum = ws + 532480;                  // 8
    int* idxbuf = (int*)(ws + 532488);            // 81920 (ends 614408)
    unsigned* hist16 = (unsigned*)(ws + 614408);  // 524288 (ends 1138696)
    int* tbuf = (int*)(ws + 1138696);             // 56000 (ends 1194696)
    ushort* pk = (ushort*)(ws + PK_F32_OFF);      // 2629632 bf16 = 5.26 MB

    hipMemsetAsync(hist16, 0, 524288 * sizeof(unsigned), stream);

    k_logits<<<1024, 256, 0, stream>>>(x, Wdct, Wgate, logitsT, partials, y, hist16);
    k_misc<<<8 + PK_TOTAL / 1024, 1024, 0, stream>>>(logitsT, partials, colsum,
                                                     idxbuf, hist16, tbuf,
                                                     W1, A1, B1, W2, A2, B2, pk);
    k_expert<<<NEXP * TILES_PER_E, 256, 0, stream>>>(x, band, b1, b2, pk,
                                                     logitsT, colsum, idxbuf, y);
}

// Round 15
// 352.279 us; speedup vs baseline: 1.0451x; 1.0451x over previous
//
#include <hip/hip_runtime.h>
#include <hip/hip_bf16.h>
#include <math.h>

#define NTOK 65536
#define DIN 256
#define DOUT 256
#define HID 512
#define NEXP 8
#define NBAND 4
#define RANK 8
#define CAP 10240
#define NTILE 64
#define TILES_PER_E (CAP / NTILE)  // 160
#define TIEMAX 7000

// packed bf16 weight region (ushort elements), offsets in elements
#define W1CAT_PER_E (34 * 9 * 512)            // 156672
#define B1CAT_OFF   (NEXP * W1CAT_PER_E)      // 1253376
#define B1CAT_PER_E (32 * 512)                // 16384
#define W2CAT_OFF   (B1CAT_OFF + NEXP * B1CAT_PER_E)  // 1384448
#define W2CAT_PER_E (18 * 16 * 512)           // 147456
#define B2CAT_OFF   (W2CAT_OFF + NEXP * W2CAT_PER_E)  // 2564096
#define B2CAT_PER_E (16 * 512)                // 8192
#define PK_TOTAL    (B2CAT_OFF + NEXP * B2CAT_PER_E)  // 2629632 = 2568*1024
#define PK_F32_OFF  1200000                   // f32-word offset of packed region in ws

typedef short s16x8 __attribute__((ext_vector_type(8)));
typedef float f32x4 __attribute__((ext_vector_type(4)));

__device__ __forceinline__ unsigned key_of(float f) {
    unsigned u = __float_as_uint(f);
    return (u & 0x80000000u) ? ~u : (u | 0x80000000u);
}
// fast tanh-gelu: tanh(z) = 1 - 2/(e^{2z}+1)  ->  gelu(v) = v*(1 - rcp(e^{2z}+1))
__device__ __forceinline__ float gelu_fast(float v) {
    const float c = 0.7978845608028654f;
    float z = c * (v + 0.044715f * v * v * v);
    float e = __expf(2.0f * z);              // inf for large z -> rcp -> 0 (ok)
    return v * (1.0f - __builtin_amdgcn_rcpf(e + 1.0f));
}
__device__ __forceinline__ ushort f2bf(float f) {  // RNE f32->bf16
    unsigned u = __float_as_uint(f);
    return (ushort)((u + 0x7FFFu + ((u >> 16) & 1u)) >> 16);
}
// async global->LDS DMA, 16B/lane; dest = uniform LDS base + lane*16
__device__ __forceinline__ void gl_lds16(const ushort* g, ushort* l) {
    __builtin_amdgcn_global_load_lds(
        (const __attribute__((address_space(1))) unsigned int*)g,
        (__attribute__((address_space(3))) unsigned int*)l, 16, 0, 0);
}

// ---------------- gating GEMV + weff-fold + y-zero + 16-bit key histogram ---
__global__ __launch_bounds__(256) void k_logits(const float* __restrict__ x,
                                                const float* __restrict__ Wdct,
                                                const float* __restrict__ Wgate,
                                                float* __restrict__ logitsT,
                                                float* __restrict__ partials,
                                                float* __restrict__ y,
                                                unsigned* __restrict__ hist16) {
    __shared__ float wefft[8][257];   // [e][d], padded row
    __shared__ float pr[4][8];
    int tid = threadIdx.x, w = tid >> 6, lane = tid & 63;

    // fold weff: thread d computes row d (same accumulation order as before)
    {
        int d = tid;
        float acc[8];
#pragma unroll
        for (int e = 0; e < 8; ++e) acc[e] = Wgate[d * 8 + e];
        for (int f = 0; f < 64; ++f) {
            float wv = Wdct[d * 64 + f];
#pragma unroll
            for (int e = 0; e < 8; ++e) acc[e] += wv * Wgate[(256 + f) * 8 + e];
        }
#pragma unroll
        for (int e = 0; e < 8; ++e) wefft[e][d] = acc[e];
    }

    // zero this block's 64 output rows
    {
        float4 z = {0.f, 0.f, 0.f, 0.f};
        float4* yp = (float4*)(y + (size_t)blockIdx.x * 64 * DOUT);
        for (int i = tid; i < 4096; i += 256) yp[i] = z;
    }
    __syncthreads();

    float wje[4][8];
#pragma unroll
    for (int j = 0; j < 4; ++j)
#pragma unroll
        for (int e = 0; e < 8; ++e) wje[j][e] = wefft[e][lane * 4 + j];

    int wid = blockIdx.x * 4 + w;       // 0..4095
    int nbase = wid * 16;
    float es = 0.f;
    for (int t = 0; t < 16; ++t) {
        int n = nbase + t;
        float4 v = *(const float4*)(x + (size_t)n * DIN + lane * 4);
        float acc[8];
#pragma unroll
        for (int e = 0; e < 8; ++e) acc[e] = 0.f;
#pragma unroll
        for (int j = 0; j < 4; ++j) {
            float vj = (j == 0) ? v.x : (j == 1) ? v.y : (j == 2) ? v.z : v.w;
#pragma unroll
            for (int e = 0; e < 8; ++e) acc[e] += vj * wje[j][e];
        }
#pragma unroll
        for (int off = 1; off < 64; off <<= 1) {
#pragma unroll
            for (int e = 0; e < 8; ++e) acc[e] += __shfl_xor(acc[e], off);
        }
        float out = acc[0];
#pragma unroll
        for (int e = 1; e < 8; ++e) if (lane == e) out = acc[e];
        if (lane < 8) {
            logitsT[(size_t)lane * NTOK + n] = out;
            es += expf(out);
            atomicAdd(&hist16[((size_t)lane << 16) + (key_of(out) >> 16)], 1u);
        }
    }
    if (lane < 8) pr[w][lane] = es;
    __syncthreads();
    if (tid < 8) partials[(size_t)tid * 1024 + blockIdx.x] =
        pr[0][tid] + pr[1][tid] + pr[2][tid] + pr[3][tid];
}

// ---------------- fused: top-CAP select (blocks 0..7) || weight pack --------
__global__ __launch_bounds__(1024) void k_misc(const float* __restrict__ logitsT,
                                               const float* __restrict__ partials,
                                               float* __restrict__ colsum,
                                               int* __restrict__ idxbuf,
                                               const unsigned* __restrict__ hist16,
                                               int* __restrict__ tbuf,
                                               const float* __restrict__ W1,
                                               const float* __restrict__ A1,
                                               const float* __restrict__ B1,
                                               const float* __restrict__ W2,
                                               const float* __restrict__ A2,
                                               const float* __restrict__ B2,
                                               ushort* __restrict__ pk) {
    if (blockIdx.x >= 8) {
        // ---- weight packing branch ----
        int id = (blockIdx.x - 8) * 1024 + threadIdx.x;
        if (id >= PK_TOTAL) return;
        float val;
        if (id < B1CAT_OFF) {
            int e = id / W1CAT_PER_E, rem = id % W1CAT_PER_E;
            int t = rem / (9 * 512); rem %= 9 * 512;
            int s = rem / 512; int q = rem & 511;
            int l = q >> 3, j = q & 7;
            int k = s * 32 + ((l >> 4) << 3) + j;
            int col = t * 16 + (l & 15);
            if (k > 256) val = 0.f;
            else if (col < 512) val = W1[((size_t)e * 257 + k) * 512 + col];
            else {
                int cu = col - 512;
                val = A1[(((size_t)e * NBAND + (cu >> 3)) * 257 + k) * RANK + (cu & 7)];
            }
        } else if (id < W2CAT_OFF) {
            int id2 = id - B1CAT_OFF;
            int e = id2 / B1CAT_PER_E, rem = id2 % B1CAT_PER_E;
            int t = rem / 512; int q = rem & 511;
            int l = q >> 3, j = q & 7;
            int k32 = ((l >> 4) << 3) + j;
            int col = t * 16 + (l & 15);
            val = 2.0f * B1[(((size_t)e * NBAND + (k32 >> 3)) * RANK + (k32 & 7)) * 512 + col];
        } else if (id < B2CAT_OFF) {
            int id2 = id - W2CAT_OFF;
            int e = id2 / W2CAT_PER_E, rem = id2 % W2CAT_PER_E;
            int t = rem / (16 * 512); rem %= 16 * 512;
            int s = rem / 512; int q = rem & 511;
            int l = q >> 3, j = q & 7;
            int k = s * 32 + ((l >> 4) << 3) + j;
            int col = t * 16 + (l & 15);
            if (col < 256) val = W2[((size_t)e * 512 + k) * 256 + col];
            else {
                int cv = col - 256;
                val = A2[(((size_t)e * NBAND + (cv >> 3)) * 512 + k) * RANK + (cv & 7)];
            }
        } else {
            int id2 = id - B2CAT_OFF;
            int e = id2 / B2CAT_PER_E, rem = id2 % B2CAT_PER_E;
            int t = rem / 512; int q = rem & 511;
            int l = q >> 3, j = q & 7;
            int k32 = ((l >> 4) << 3) + j;
            int col = t * 16 + (l & 15);
            val = 2.0f * B2[(((size_t)e * NBAND + (k32 >> 3)) * RANK + (k32 & 7)) * 256 + col];
        }
        pk[id] = f2bf(val);
        return;
    }
    // ---- top-CAP selection branch (one block per expert) ----
    __shared__ unsigned chunk[1024];
    __shared__ float ssum[16];
    __shared__ unsigned sval[2];   // threshold bin B, rem
    __shared__ unsigned scnt, stcnt;
    int e = blockIdx.x, tid = threadIdx.x, w = tid >> 6, lane = tid & 63;
    const float* lp = logitsT + (size_t)e * NTOK;
    const unsigned* h = hist16 + ((size_t)e << 16);
    int* tb = tbuf + (size_t)e * TIEMAX;

    // colsum finalize
    {
        float s = partials[(size_t)e * 1024 + tid];
#pragma unroll
        for (int off = 32; off > 0; off >>= 1) s += __shfl_xor(s, off);
        if (lane == 0) ssum[w] = s;
        __syncthreads();
        if (tid == 0) {
            float t = 0.f;
#pragma unroll
            for (int i = 0; i < 16; ++i) t += ssum[i];
            colsum[e] = t;
        }
    }
    if (tid == 0) { scnt = 0; stcnt = 0; }

    // threshold: suffix-scan of 64K bins (each thread owns 64 bins)
    {
        unsigned csum = 0;
        for (int i = 0; i < 64; ++i) csum += h[tid * 64 + i];
        chunk[tid] = csum;
        __syncthreads();
        for (int off = 1; off < 1024; off <<= 1) {
            unsigned add = (tid + off < 1024) ? chunk[tid + off] : 0u;
            __syncthreads();
            chunk[tid] += add;
            __syncthreads();
        }
        unsigned above = (tid == 1023) ? 0u : chunk[tid + 1];
        unsigned s = above;
        for (int b = 63; b >= 0; --b) {
            unsigned prev = s;
            s += h[tid * 64 + b];
            if (s >= (unsigned)CAP && prev < (unsigned)CAP) {
                sval[0] = (unsigned)(tid * 64 + b);
                sval[1] = (unsigned)CAP - prev;
            }
        }
        __syncthreads();
    }
    unsigned B = sval[0], rem = sval[1];

    // single select pass
    for (int it = 0; it < 64; ++it) {
        int n = it * 1024 + tid;
        unsigned k16 = key_of(lp[n]) >> 16;
        if (k16 > B) {
            unsigned pos = atomicAdd(&scnt, 1u);
            idxbuf[e * CAP + pos] = n;
        } else if (k16 == B) {
            unsigned tp = atomicAdd(&stcnt, 1u);
            if (tp < TIEMAX) tb[tp] = n;
        }
    }
    __syncthreads();
    int m = (int)min(stcnt, (unsigned)TIEMAX), r = (int)rem, base = CAP - r;
    if (m == r) {
        for (int i = tid; i < m; i += 1024) idxbuf[e * CAP + base + i] = tb[i];
    } else {
        // rank ties by (full key desc, index asc); r best get slots
        for (int i = tid; i < m; i += 1024) {
            int my = tb[i];
            unsigned km = key_of(lp[my]);
            int rank = 0;
            for (int j = 0; j < m; ++j) {
                int oj = tb[j];
                unsigned kj = key_of(lp[oj]);
                rank += (kj > km) || (kj == km && oj < my);
            }
            if (rank < r) idxbuf[e * CAP + base + rank] = my;
        }
    }
}

// ---------------- fused expert MLP: async W1 staging, direct W2 -------------
// W1 double-buffered in LDS, filled via global_load_lds (zero staging VGPRs,
// zero ds_writes, vmcnt drained by the one end-of-phase barrier). W2 read
// direct from global: 18 independent loads/wave/phase, shared via L1 across
// the 4 waves + 3 co-resident blocks (all same expert: e = bid&7 = XCD id).
// LDS ~42.7KB + ~142 total VGPR -> 3 blocks/CU (12 waves) spill-free.
__global__ __launch_bounds__(256, 3) void k_expert(
    const float* __restrict__ x, const int* __restrict__ band,
    const float* __restrict__ b1, const float* __restrict__ b2,
    const ushort* __restrict__ pk,
    const float* __restrict__ logitsT,
    const float* __restrict__ colsum, const int* __restrict__ idxbuf,
    float* __restrict__ y) {
    __shared__ ushort bW1[2][9216];     // phase W1: 18 chunks x 512 (2 tiles x 9 ksteps)
    __shared__ ushort sc[4][640];       // per-wave transpose scratch
    __shared__ int s_tok[4][16];
    __shared__ int s_band[4][16];
    __shared__ float s_g[4][16];

    int tid = threadIdx.x, w = tid >> 6, lane = tid & 63;
    int bid = blockIdx.x;
    int e = bid & 7;            // XCD-pinned expert
    int tile = bid >> 3;        // 0..159

    if (lane < 16) {
        int n = idxbuf[e * CAP + tile * NTILE + w * 16 + lane];
        s_tok[w][lane] = n;
        s_band[w][lane] = band[n];
        s_g[w][lane] = expf(logitsT[(size_t)e * NTOK + n]) / colsum[e];
    }

    int l15 = lane & 15, lg = lane >> 4;
    ushort* scw = &sc[w][0];

    const ushort* w1base = pk + (size_t)e * W1CAT_PER_E;
    const ushort* b1base = pk + B1CAT_OFF + (size_t)e * B1CAT_PER_E;
    const ushort* w2base = pk + W2CAT_OFF + (size_t)e * W2CAT_PER_E;
    const ushort* b2base = pk + B2CAT_OFF + (size_t)e * B2CAT_PER_E;

    // ---- issue phase-0 W1 staging (async DMA to LDS) ----
    for (int c = w; c < 18; c += 4)
        gl_lds16(w1base + (size_t)c * 512 + lane * 8, &bW1[0][c * 512]);

    // ---- A-frags for layer 1 (K=288: 9 ksteps) ----
    s16x8 a1[9];
    {
        int mytok = s_tok[w][l15];
        const float* xrow = x + (size_t)mytok * DIN;
        int kg = lg << 3;
#pragma unroll
        for (int s = 0; s < 8; ++s) {
            float4 p = *(const float4*)&xrow[s * 32 + kg];
            float4 q = *(const float4*)&xrow[s * 32 + kg + 4];
            s16x8 a;
            a[0] = (short)f2bf(p.x); a[1] = (short)f2bf(p.y);
            a[2] = (short)f2bf(p.z); a[3] = (short)f2bf(p.w);
            a[4] = (short)f2bf(q.x); a[5] = (short)f2bf(q.y);
            a[6] = (short)f2bf(q.z); a[7] = (short)f2bf(q.w);
            a1[s] = a;
        }
        s16x8 a = (s16x8)(short)0;
        if (lane < 16) a[0] = (short)f2bf((float)s_band[w][l15] * 0.25f);
        a1[8] = a;
    }

    // ---- LoRA1 u = xe @ A1cat (tiles 32,33, direct global), band-mask ----
    s16x8 ufrag;
    {
#pragma unroll
        for (int t = 32; t <= 33; ++t) {
            f32x4 acc = {0.f, 0.f, 0.f, 0.f};
#pragma unroll
            for (int s = 0; s < 9; ++s) {
                s16x8 b = *(const s16x8*)(w1base + ((size_t)t * 9 + s) * 512 + lane * 8);
                acc = __builtin_amdgcn_mfma_f32_16x16x32_bf16(a1[s], b, acc, 0, 0, 0);
            }
            int colbase = (t - 32) * 16 + l15;
#pragma unroll
            for (int r = 0; r < 4; ++r) {
                int row = lg * 4 + r;
                float v = ((colbase >> 3) == s_band[w][row]) ? acc[r] : 0.f;
                scw[row * 40 + colbase] = f2bf(v);
            }
        }
        ufrag = *(const s16x8*)&scw[l15 * 40 + lg * 8];
    }

    // ---- layer2 accumulators (bias-initialized), LoRA2 accumulators ----
    f32x4 oacc[16];
#pragma unroll
    for (int t2 = 0; t2 < 16; ++t2) {
        float bv = b2[(size_t)e * DOUT + t2 * 16 + l15];
        oacc[t2] = (f32x4){bv, bv, bv, bv};
    }
    f32x4 vacc[2];
    vacc[0] = (f32x4){0.f, 0.f, 0.f, 0.f};
    vacc[1] = (f32x4){0.f, 0.f, 0.f, 0.f};

    __syncthreads();   // drains phase-0 DMA (vmcnt before barrier)

    int cur = 0;
#pragma unroll 1
    for (int p = 0; p < 16; ++p) {
        // (a) async-stage phase p+1's W1 into the other buffer
        if (p < 15) {
            const ushort* src = w1base + (size_t)(18 * (p + 1)) * 512;
            ushort* dst = &bW1[cur ^ 1][0];
            for (int c = w; c < 18; c += 4)
                gl_lds16(src + (size_t)c * 512 + lane * 8, dst + c * 512);
        }
        // (b) layer 1 from bW1[cur] -> gelu -> transpose -> hfrag
#pragma unroll
        for (int half = 0; half < 2; ++half) {
            int t = p * 2 + half;
            float bv = b1[(size_t)e * HID + t * 16 + l15];
            f32x4 acc = {bv, bv, bv, bv};
#pragma unroll
            for (int s = 0; s < 9; ++s) {
                s16x8 b = *(const s16x8*)(&bW1[cur][(half * 9 + s) * 512] + lane * 8);
                acc = __builtin_amdgcn_mfma_f32_16x16x32_bf16(a1[s], b, acc, 0, 0, 0);
            }
            {
                s16x8 b = *(const s16x8*)(b1base + (size_t)t * 512 + lane * 8);
                acc = __builtin_amdgcn_mfma_f32_16x16x32_bf16(ufrag, b, acc, 0, 0, 0);
            }
#pragma unroll
            for (int r = 0; r < 4; ++r) {
                int row = lg * 4 + r;
                scw[row * 40 + half * 16 + l15] = f2bf(gelu_fast(acc[r]));
            }
        }
        s16x8 hfrag = *(const s16x8*)&scw[l15 * 40 + lg * 8];
        // (c) layer 2: direct-global W2 (18 independent loads, L1-shared)
#pragma unroll
        for (int t2 = 0; t2 < 16; ++t2) {
            s16x8 b = *(const s16x8*)(w2base + ((size_t)t2 * 16 + p) * 512 + lane * 8);
            oacc[t2] = __builtin_amdgcn_mfma_f32_16x16x32_bf16(hfrag, b, oacc[t2], 0, 0, 0);
        }
#pragma unroll
        for (int i = 0; i < 2; ++i) {
            s16x8 b = *(const s16x8*)(w2base + ((size_t)(16 + i) * 16 + p) * 512 + lane * 8);
            vacc[i] = __builtin_amdgcn_mfma_f32_16x16x32_bf16(hfrag, b, vacc[i], 0, 0, 0);
        }
        // (d) one barrier: all reads of bW1[cur] done + next-phase DMA landed
        __syncthreads();
        cur ^= 1;
    }

    // ---- LoRA2: band-mask v, transpose -> vfrag, fold through B2cat ----
    s16x8 vfrag;
    {
#pragma unroll
        for (int i = 0; i < 2; ++i) {
            int colbase = i * 16 + l15;
#pragma unroll
            for (int r = 0; r < 4; ++r) {
                int row = lg * 4 + r;
                float v = ((colbase >> 3) == s_band[w][row]) ? vacc[i][r] : 0.f;
                scw[row * 40 + colbase] = f2bf(v);
            }
        }
        vfrag = *(const s16x8*)&scw[l15 * 40 + lg * 8];
    }

    float g4[4];
    int tok4[4];
#pragma unroll
    for (int r = 0; r < 4; ++r) {
        int row = lg * 4 + r;
        g4[r] = s_g[w][row];
        tok4[r] = s_tok[w][row];
    }
#pragma unroll
    for (int t2 = 0; t2 < 16; ++t2) {
        s16x8 b = *(const s16x8*)(b2base + (size_t)t2 * 512 + lane * 8);
        f32x4 acc = __builtin_amdgcn_mfma_f32_16x16x32_bf16(vfrag, b, oacc[t2], 0, 0, 0);
        int col = t2 * 16 + l15;
#pragma unroll
        for (int r = 0; r < 4; ++r) {
            atomicAdd(&y[(size_t)tok4[r] * DOUT + col], g4[r] * acc[r]);
        }
    }
}

extern "C" void kernel_launch(void* const* d_in, const int* in_sizes, int n_in,
                              void* d_out, int out_size, void* d_ws, size_t ws_size,
                              hipStream_t stream) {
    const float* x = (const float*)d_in[0];
    const int* band = (const int*)d_in[1];
    const float* Wdct = (const float*)d_in[2];
    const float* Wgate = (const float*)d_in[3];
    const float* W1 = (const float*)d_in[4];
    const float* b1 = (const float*)d_in[5];
    const float* A1 = (const float*)d_in[6];
    const float* B1 = (const float*)d_in[7];
    const float* W2 = (const float*)d_in[8];
    const float* b2 = (const float*)d_in[9];
    const float* A2 = (const float*)d_in[10];
    const float* B2 = (const float*)d_in[11];
    float* y = (float*)d_out;

    float* ws = (float*)d_ws;
    float* logitsT = ws;                          // 0 .. 524288
    float* partials = ws + 524288;                // 8192 (8 x 1024)
    float* colsum = ws + 532480;                  // 8
    int* idxbuf = (int*)(ws + 532488);            // 81920 (ends 614408)
    unsigned* hist16 = (unsigned*)(ws + 614408);  // 524288 (ends 1138696)
    int* tbuf = (int*)(ws + 1138696);             // 56000 (ends 1194696)
    ushort* pk = (ushort*)(ws + PK_F32_OFF);      // 2629632 bf16 = 5.26 MB

    hipMemsetAsync(hist16, 0, 524288 * sizeof(unsigned), stream);

    k_logits<<<1024, 256, 0, stream>>>(x, Wdct, Wgate, logitsT, partials, y, hist16);
    k_misc<<<8 + PK_TOTAL / 1024, 1024, 0, stream>>>(logitsT, partials, colsum,
                                                     idxbuf, hist16, tbuf,
                                                     W1, A1, B1, W2, A2, B2, pk);
    k_expert<<<NEXP * TILES_PER_E, 256, 0, stream>>>(x, band, b1, b2, pk,
                                                     logitsT, colsum, idxbuf, y);
}

// Round 16
// 288.126 us; speedup vs baseline: 1.2777x; 1.2227x over previous
//
#include <hip/hip_runtime.h>
#include <hip/hip_bf16.h>
#include <math.h>

#define NTOK 65536
#define DIN 256
#define DOUT 256
#define HID 512
#define NEXP 8
#define NBAND 4
#define RANK 8
#define CAP 10240
#define NTILE 64
#define TILES_PER_E (CAP / NTILE)  // 160

// packed bf16 weight region (ushort elements), offsets in elements
#define W1CAT_PER_E (34 * 9 * 512)            // 156672
#define B1CAT_OFF   (NEXP * W1CAT_PER_E)      // 1253376
#define B1CAT_PER_E (32 * 512)                // 16384
#define W2CAT_OFF   (B1CAT_OFF + NEXP * B1CAT_PER_E)  // 1384448
#define W2CAT_PER_E (18 * 16 * 512)           // 147456
#define B2CAT_OFF   (W2CAT_OFF + NEXP * W2CAT_PER_E)  // 2564096
#define B2CAT_PER_E (16 * 512)                // 8192
#define PK_TOTAL    (B2CAT_OFF + NEXP * B2CAT_PER_E)  // 2629632 = 2568*1024
#define PK_F32_OFF  1200000                   // f32-word offset of packed region in ws

typedef short s16x8 __attribute__((ext_vector_type(8)));
typedef float f32x4 __attribute__((ext_vector_type(4)));

__device__ __forceinline__ unsigned key_of(float f) {
    unsigned u = __float_as_uint(f);
    return (u & 0x80000000u) ? ~u : (u | 0x80000000u);
}
// fast tanh-gelu: tanh(z) = 1 - 2/(e^{2z}+1)  ->  gelu(v) = v*(1 - rcp(e^{2z}+1))
__device__ __forceinline__ float gelu_fast(float v) {
    const float c = 0.7978845608028654f;
    float z = c * (v + 0.044715f * v * v * v);
    float e = __expf(2.0f * z);              // inf for large z -> rcp -> 0 (ok)
    return v * (1.0f - __builtin_amdgcn_rcpf(e + 1.0f));
}
__device__ __forceinline__ ushort f2bf(float f) {  // RNE f32->bf16
    unsigned u = __float_as_uint(f);
    return (ushort)((u + 0x7FFFu + ((u >> 16) & 1u)) >> 16);
}

// ---------------- gating GEMV + fused weff-fold + y-zeroing -----------------
// Weff = Wg_x + Wdct @ Wg_f computed per-block into LDS (transposed, padded).
// logits math bit-identical to prior rounds (same FMA order).
__global__ __launch_bounds__(256) void k_logits(const float* __restrict__ x,
                                                const float* __restrict__ Wdct,
                                                const float* __restrict__ Wgate,
                                                float* __restrict__ logitsT,
                                                float* __restrict__ partials,
                                                float* __restrict__ y) {
    __shared__ float wefft[8][257];   // [e][d], padded row
    __shared__ float pr[4][8];
    int tid = threadIdx.x, w = tid >> 6, lane = tid & 63;

    // fold weff: thread d computes row d (same accumulation order as k_foldw)
    {
        int d = tid;
        float acc[8];
#pragma unroll
        for (int e = 0; e < 8; ++e) acc[e] = Wgate[d * 8 + e];
        for (int f = 0; f < 64; ++f) {
            float wv = Wdct[d * 64 + f];
#pragma unroll
            for (int e = 0; e < 8; ++e) acc[e] += wv * Wgate[(256 + f) * 8 + e];
        }
#pragma unroll
        for (int e = 0; e < 8; ++e) wefft[e][d] = acc[e];
    }

    // zero this block's 64 output rows (64 tok x 256 f32 = 4096 float4)
    {
        float4 z = {0.f, 0.f, 0.f, 0.f};
        float4* yp = (float4*)(y + (size_t)blockIdx.x * 64 * DOUT);
        for (int i = tid; i < 4096; i += 256) yp[i] = z;
    }
    __syncthreads();

    // lane-resident Weff rows lane*4..lane*4+3 (scalar LDS reads, 8-way max)
    float wje[4][8];
#pragma unroll
    for (int j = 0; j < 4; ++j)
#pragma unroll
        for (int e = 0; e < 8; ++e) wje[j][e] = wefft[e][lane * 4 + j];

    int wid = blockIdx.x * 4 + w;       // 0..4095
    int nbase = wid * 16;
    float es = 0.f;
    for (int t = 0; t < 16; ++t) {
        int n = nbase + t;
        float4 v = *(const float4*)(x + (size_t)n * DIN + lane * 4);
        float acc[8];
#pragma unroll
        for (int e = 0; e < 8; ++e) acc[e] = 0.f;
#pragma unroll
        for (int j = 0; j < 4; ++j) {
            float vj = (j == 0) ? v.x : (j == 1) ? v.y : (j == 2) ? v.z : v.w;
#pragma unroll
            for (int e = 0; e < 8; ++e) acc[e] += vj * wje[j][e];
        }
#pragma unroll
        for (int off = 1; off < 64; off <<= 1) {
#pragma unroll
            for (int e = 0; e < 8; ++e) acc[e] += __shfl_xor(acc[e], off);
        }
        float out = acc[0];
#pragma unroll
        for (int e = 1; e < 8; ++e) if (lane == e) out = acc[e];
        if (lane < 8) {
            logitsT[(size_t)lane * NTOK + n] = out;
            es += expf(out);
        }
    }
    if (lane < 8) pr[w][lane] = es;
    __syncthreads();
    if (tid < 8) partials[(size_t)tid * 1024 + blockIdx.x] =
        pr[0][tid] + pr[1][tid] + pr[2][tid] + pr[3][tid];
}

// ---------------- fused: top-CAP select (blocks 0..7) || weight pack --------
__global__ __launch_bounds__(1024) void k_misc(const float* __restrict__ logitsT,
                                               const float* __restrict__ partials,
                                               float* __restrict__ colsum,
                                               int* __restrict__ idxbuf,
                                               const float* __restrict__ W1,
                                               const float* __restrict__ A1,
                                               const float* __restrict__ B1,
                                               const float* __restrict__ W2,
                                               const float* __restrict__ A2,
                                               const float* __restrict__ B2,
                                               ushort* __restrict__ pk) {
    if (blockIdx.x >= 8) {
        // ---- weight packing branch ----
        int id = (blockIdx.x - 8) * 1024 + threadIdx.x;
        if (id >= PK_TOTAL) return;
        float val;
        if (id < B1CAT_OFF) {
            int e = id / W1CAT_PER_E, rem = id % W1CAT_PER_E;
            int t = rem / (9 * 512); rem %= 9 * 512;
            int s = rem / 512; int q = rem & 511;
            int l = q >> 3, j = q & 7;
            int k = s * 32 + ((l >> 4) << 3) + j;
            int col = t * 16 + (l & 15);
            if (k > 256) val = 0.f;
            else if (col < 512) val = W1[((size_t)e * 257 + k) * 512 + col];
            else {
                int cu = col - 512;
                val = A1[(((size_t)e * NBAND + (cu >> 3)) * 257 + k) * RANK + (cu & 7)];
            }
        } else if (id < W2CAT_OFF) {
            int id2 = id - B1CAT_OFF;
            int e = id2 / B1CAT_PER_E, rem = id2 % B1CAT_PER_E;
            int t = rem / 512; int q = rem & 511;
            int l = q >> 3, j = q & 7;
            int k32 = ((l >> 4) << 3) + j;
            int col = t * 16 + (l & 15);
            val = 2.0f * B1[(((size_t)e * NBAND + (k32 >> 3)) * RANK + (k32 & 7)) * 512 + col];
        } else if (id < B2CAT_OFF) {
            int id2 = id - W2CAT_OFF;
            int e = id2 / W2CAT_PER_E, rem = id2 % W2CAT_PER_E;
            int t = rem / (16 * 512); rem %= 16 * 512;
            int s = rem / 512; int q = rem & 511;
            int l = q >> 3, j = q & 7;
            int k = s * 32 + ((l >> 4) << 3) + j;
            int col = t * 16 + (l & 15);
            if (col < 256) val = W2[((size_t)e * 512 + k) * 256 + col];
            else {
                int cv = col - 256;
                val = A2[(((size_t)e * NBAND + (cv >> 3)) * 512 + k) * RANK + (cv & 7)];
            }
        } else {
            int id2 = id - B2CAT_OFF;
            int e = id2 / B2CAT_PER_E, rem = id2 % B2CAT_PER_E;
            int t = rem / 512; int q = rem & 511;
            int l = q >> 3, j = q & 7;
            int k32 = ((l >> 4) << 3) + j;
            int col = t * 16 + (l & 15);
            val = 2.0f * B2[(((size_t)e * NBAND + (k32 >> 3)) * RANK + (k32 & 7)) * 256 + col];
        }
        pk[id] = f2bf(val);
        return;
    }
    // ---- top-CAP selection branch (one block per expert) ----
    __shared__ unsigned subh[16][257];
    __shared__ unsigned bins[256];
    __shared__ float ssum[16];
    __shared__ unsigned sval[2];   // pref, rem
    __shared__ unsigned scnt, stcnt;
    __shared__ int ties_l[2048];
    int e = blockIdx.x, tid = threadIdx.x, w = tid >> 6, lane = tid & 63;
    const float* lp = logitsT + (size_t)e * NTOK;

    {
        float s = partials[(size_t)e * 1024 + tid];
#pragma unroll
        for (int off = 32; off > 0; off >>= 1) s += __shfl_xor(s, off);
        if (lane == 0) ssum[w] = s;
        __syncthreads();
        if (tid == 0) {
            float t = 0.f;
#pragma unroll
            for (int i = 0; i < 16; ++i) t += ssum[i];
            colsum[e] = t;
        }
    }

    unsigned pref = 0, rem = CAP;
    for (int p = 0; p < 4; ++p) {
        int shift = 24 - 8 * p;
        for (int i = tid; i < 16 * 257; i += 1024) ((unsigned*)subh)[i] = 0;
        __syncthreads();
        for (int it = 0; it < 64; ++it) {
            int n = it * 1024 + tid;
            unsigned k = key_of(lp[n]);
            bool ok = (p == 0) || ((k >> (shift + 8)) == pref);
            if (ok) atomicAdd(&subh[w][(k >> shift) & 255u], 1u);
        }
        __syncthreads();
        if (tid < 256) {
            unsigned c = 0;
#pragma unroll
            for (int ww = 0; ww < 16; ++ww) c += subh[ww][tid];
            bins[tid] = c;
        }
        __syncthreads();
        for (int off = 1; off < 256; off <<= 1) {
            unsigned add = (tid < 256 && tid + off < 256) ? bins[tid + off] : 0u;
            __syncthreads();
            if (tid < 256) bins[tid] += add;
            __syncthreads();
        }
        if (tid < 256) {
            unsigned snext = (tid == 255) ? 0u : bins[tid + 1];
            if (bins[tid] >= rem && snext < rem) {
                sval[0] = (pref << 8) | (unsigned)tid;
                sval[1] = rem - snext;
            }
        }
        __syncthreads();
        pref = sval[0];
        rem = sval[1];
        __syncthreads();
    }

    if (tid == 0) { scnt = 0; stcnt = 0; }
    __syncthreads();
    unsigned T = pref;
    for (int it = 0; it < 64; ++it) {
        int n = it * 1024 + tid;
        unsigned k = key_of(lp[n]);
        if (k > T) {
            unsigned pos = atomicAdd(&scnt, 1u);
            idxbuf[e * CAP + pos] = n;
        } else if (k == T) {
            unsigned tp = atomicAdd(&stcnt, 1u);
            if (tp < 2048) ties_l[tp] = n;
        }
    }
    __syncthreads();
    int m = (int)stcnt, r = (int)rem, base = CAP - r;
    if (m == r) {
        for (int i = tid; i < m; i += 1024) idxbuf[e * CAP + base + i] = ties_l[i];
    } else {
        for (int i = tid; i < m; i += 1024) {
            int my = ties_l[i];
            int rank = 0;
            for (int j = 0; j < m; ++j) rank += (ties_l[j] < my);
            if (rank < r) idxbuf[e * CAP + base + rank] = my;
        }
    }
}

// ---------------- fused expert MLP: block-cooperative LDS staging -----------
// Single-buffer staged W1/W2 (T14 reg-split overlaps load latency with
// compute). No sched pins: compiler inserts fine-grained lgkmcnt itself.
__global__ __launch_bounds__(256, 2) void k_expert(
    const float* __restrict__ x, const int* __restrict__ band,
    const float* __restrict__ b1, const float* __restrict__ b2,
    const ushort* __restrict__ pk,
    const float* __restrict__ logitsT,
    const float* __restrict__ colsum, const int* __restrict__ idxbuf,
    float* __restrict__ y) {
    __shared__ ushort bW1[9216];        // 18 chunks x 512 (tiles 2p,2p+1 x 9 ksteps)
    __shared__ ushort bW2[9216];        // 18 chunks x 512 (t2 0..17, slice p)
    __shared__ ushort sc[4][640];       // per-wave transpose scratch
    __shared__ int s_tok[4][16];
    __shared__ int s_band[4][16];
    __shared__ float s_g[4][16];

    int tid = threadIdx.x, w = tid >> 6, lane = tid & 63;
    int bid = blockIdx.x;
    int e = bid & 7;            // XCD-pinned expert
    int tile = bid >> 3;        // 0..159

    if (lane < 16) {
        int n = idxbuf[e * CAP + tile * NTILE + w * 16 + lane];
        s_tok[w][lane] = n;
        s_band[w][lane] = band[n];
        s_g[w][lane] = expf(logitsT[(size_t)e * NTOK + n]) / colsum[e];
    }

    int l15 = lane & 15, lg = lane >> 4;
    ushort* scw = &sc[w][0];

    // ---- A-frags for layer 1 (K=288: 9 ksteps) ----
    s16x8 a1[9];
    {
        int mytok = s_tok[w][l15];
        const float* xrow = x + (size_t)mytok * DIN;
        int kg = lg << 3;
#pragma unroll
        for (int s = 0; s < 8; ++s) {
            float4 p = *(const float4*)&xrow[s * 32 + kg];
            float4 q = *(const float4*)&xrow[s * 32 + kg + 4];
            s16x8 a;
            a[0] = (short)f2bf(p.x); a[1] = (short)f2bf(p.y);
            a[2] = (short)f2bf(p.z); a[3] = (short)f2bf(p.w);
            a[4] = (short)f2bf(q.x); a[5] = (short)f2bf(q.y);
            a[6] = (short)f2bf(q.z); a[7] = (short)f2bf(q.w);
            a1[s] = a;
        }
        s16x8 a = (s16x8)(short)0;
        if (lane < 16) a[0] = (short)f2bf((float)s_band[w][l15] * 0.25f);
        a1[8] = a;
    }

    const ushort* w1base = pk + (size_t)e * W1CAT_PER_E;
    const ushort* b1base = pk + B1CAT_OFF + (size_t)e * B1CAT_PER_E;
    const ushort* w2base = pk + W2CAT_OFF + (size_t)e * W2CAT_PER_E;
    const ushort* b2base = pk + B2CAT_OFF + (size_t)e * B2CAT_PER_E;

    // ---- issue prologue stage loads (phase 0) into regs ----
    s16x8 stg[9];
    if (w < 2) {
        const ushort* s0 = w2base + (size_t)(w * 9) * 16 * 512 + lane * 8;
#pragma unroll
        for (int i = 0; i < 9; ++i)
            stg[i] = *(const s16x8*)(s0 + (size_t)i * 16 * 512);
    } else {
        const ushort* s0 = w1base + (size_t)(w - 2) * 9 * 512 + lane * 8;
#pragma unroll
        for (int i = 0; i < 9; ++i)
            stg[i] = *(const s16x8*)(s0 + i * 512);
    }

    // ---- LoRA1 u = xe @ A1cat (tiles 32,33, direct global), band-mask ----
    s16x8 ufrag;
    {
#pragma unroll
        for (int t = 32; t <= 33; ++t) {
            f32x4 acc = {0.f, 0.f, 0.f, 0.f};
#pragma unroll
            for (int s = 0; s < 9; ++s) {
                s16x8 b = *(const s16x8*)(w1base + ((size_t)t * 9 + s) * 512 + lane * 8);
                acc = __builtin_amdgcn_mfma_f32_16x16x32_bf16(a1[s], b, acc, 0, 0, 0);
            }
            int colbase = (t - 32) * 16 + l15;
#pragma unroll
            for (int r = 0; r < 4; ++r) {
                int row = lg * 4 + r;
                float v = ((colbase >> 3) == s_band[w][row]) ? acc[r] : 0.f;
                scw[row * 40 + colbase] = f2bf(v);
            }
        }
        ufrag = *(const s16x8*)&scw[l15 * 40 + lg * 8];
    }

    // ---- layer2 accumulators (bias-initialized), LoRA2 accumulators ----
    f32x4 oacc[16];
#pragma unroll
    for (int t2 = 0; t2 < 16; ++t2) {
        float bv = b2[(size_t)e * DOUT + t2 * 16 + l15];
        oacc[t2] = (f32x4){bv, bv, bv, bv};
    }
    f32x4 vacc[2];
    vacc[0] = (f32x4){0.f, 0.f, 0.f, 0.f};
    vacc[1] = (f32x4){0.f, 0.f, 0.f, 0.f};

    // ---- write prologue staged regs to the buffer, sync ----
    if (w < 2) {
#pragma unroll
        for (int i = 0; i < 9; ++i)
            *(s16x8*)(&bW2[(w * 9 + i) * 512] + lane * 8) = stg[i];
    } else {
#pragma unroll
        for (int i = 0; i < 9; ++i)
            *(s16x8*)(&bW1[((w - 2) * 9 + i) * 512] + lane * 8) = stg[i];
    }
    __syncthreads();

#pragma unroll 1
    for (int p = 0; p < 16; ++p) {
        // (a) issue next phase's global loads into regs (land during compute)
        s16x8 st2[9];
        if (p < 15) {
            int p1 = p + 1;
            if (w < 2) {
                const ushort* s0 = w2base + ((size_t)(w * 9) * 16 + p1) * 512 + lane * 8;
#pragma unroll
                for (int i = 0; i < 9; ++i)
                    st2[i] = *(const s16x8*)(s0 + (size_t)i * 16 * 512);
            } else {
                int t = p1 * 2 + (w - 2);
                const ushort* s0 = w1base + (size_t)t * 9 * 512 + lane * 8;
#pragma unroll
                for (int i = 0; i < 9; ++i)
                    st2[i] = *(const s16x8*)(s0 + i * 512);
            }
        }
        // (b) compute phase p from LDS
#pragma unroll
        for (int half = 0; half < 2; ++half) {
            int t = p * 2 + half;
            float bv = b1[(size_t)e * HID + t * 16 + l15];
            f32x4 acc = {bv, bv, bv, bv};
#pragma unroll
            for (int s = 0; s < 9; ++s) {
                s16x8 b = *(const s16x8*)(&bW1[(half * 9 + s) * 512] + lane * 8);
                acc = __builtin_amdgcn_mfma_f32_16x16x32_bf16(a1[s], b, acc, 0, 0, 0);
            }
            {
                s16x8 b = *(const s16x8*)(b1base + (size_t)t * 512 + lane * 8);
                acc = __builtin_amdgcn_mfma_f32_16x16x32_bf16(ufrag, b, acc, 0, 0, 0);
            }
#pragma unroll
            for (int r = 0; r < 4; ++r) {
                int row = lg * 4 + r;
                scw[row * 40 + half * 16 + l15] = f2bf(gelu_fast(acc[r]));
            }
        }
        s16x8 hfrag = *(const s16x8*)&scw[l15 * 40 + lg * 8];
#pragma unroll
        for (int t2 = 0; t2 < 16; ++t2) {
            s16x8 b = *(const s16x8*)(&bW2[t2 * 512] + lane * 8);
            oacc[t2] = __builtin_amdgcn_mfma_f32_16x16x32_bf16(hfrag, b, oacc[t2], 0, 0, 0);
        }
#pragma unroll
        for (int i = 0; i < 2; ++i) {
            s16x8 b = *(const s16x8*)(&bW2[(16 + i) * 512] + lane * 8);
            vacc[i] = __builtin_amdgcn_mfma_f32_16x16x32_bf16(hfrag, b, vacc[i], 0, 0, 0);
        }
        // (c) all waves done READING the buffer -> overwrite with next phase
        if (p < 15) {
            __syncthreads();
            if (w < 2) {
#pragma unroll
                for (int i = 0; i < 9; ++i)
                    *(s16x8*)(&bW2[(w * 9 + i) * 512] + lane * 8) = st2[i];
            } else {
#pragma unroll
                for (int i = 0; i < 9; ++i)
                    *(s16x8*)(&bW1[((w - 2) * 9 + i) * 512] + lane * 8) = st2[i];
            }
            __syncthreads();
        }
    }

    // ---- LoRA2: band-mask v, transpose -> vfrag, fold through B2cat ----
    s16x8 vfrag;
    {
#pragma unroll
        for (int i = 0; i < 2; ++i) {
            int colbase = i * 16 + l15;
#pragma unroll
            for (int r = 0; r < 4; ++r) {
                int row = lg * 4 + r;
                float v = ((colbase >> 3) == s_band[w][row]) ? vacc[i][r] : 0.f;
                scw[row * 40 + colbase] = f2bf(v);
            }
        }
        vfrag = *(const s16x8*)&scw[l15 * 40 + lg * 8];
    }

    float g4[4];
    int tok4[4];
#pragma unroll
    for (int r = 0; r < 4; ++r) {
        int row = lg * 4 + r;
        g4[r] = s_g[w][row];
        tok4[r] = s_tok[w][row];
    }
#pragma unroll
    for (int t2 = 0; t2 < 16; ++t2) {
        s16x8 b = *(const s16x8*)(b2base + (size_t)t2 * 512 + lane * 8);
        f32x4 acc = __builtin_amdgcn_mfma_f32_16x16x32_bf16(vfrag, b, oacc[t2], 0, 0, 0);
        int col = t2 * 16 + l15;
#pragma unroll
        for (int r = 0; r < 4; ++r) {
            atomicAdd(&y[(size_t)tok4[r] * DOUT + col], g4[r] * acc[r]);
        }
    }
}

extern "C" void kernel_launch(void* const* d_in, const int* in_sizes, int n_in,
                              void* d_out, int out_size, void* d_ws, size_t ws_size,
                              hipStream_t stream) {
    const float* x = (const float*)d_in[0];
    const int* band = (const int*)d_in[1];
    const float* Wdct = (const float*)d_in[2];
    const float* Wgate = (const float*)d_in[3];
    const float* W1 = (const float*)d_in[4];
    const float* b1 = (const float*)d_in[5];
    const float* A1 = (const float*)d_in[6];
    const float* B1 = (const float*)d_in[7];
    const float* W2 = (const float*)d_in[8];
    const float* b2 = (const float*)d_in[9];
    const float* A2 = (const float*)d_in[10];
    const float* B2 = (const float*)d_in[11];
    float* y = (float*)d_out;

    float* ws = (float*)d_ws;
    float* logitsT = ws;                          // 524288 words
    float* partials = ws + 524288;                // 8192 (8 experts x 1024 blocks)
    float* colsum = ws + 532480;                  // 8
    int* idxbuf = (int*)(ws + 532488);            // 81920 (ends 614408)
    ushort* pk = (ushort*)(ws + PK_F32_OFF);      // 2629632 bf16 = 5.26 MB

    k_logits<<<1024, 256, 0, stream>>>(x, Wdct, Wgate, logitsT, partials, y);
    k_misc<<<8 + PK_TOTAL / 1024, 1024, 0, stream>>>(logitsT, partials, colsum,
                                                     idxbuf, W1, A1, B1, W2, A2,
                                                     B2, pk);
    k_expert<<<NEXP * TILES_PER_E, 256, 0, stream>>>(x, band, b1, b2, pk,
                                                     logitsT, colsum, idxbuf, y);
}

// Round 17
// 265.484 us; speedup vs baseline: 1.3867x; 1.0853x over previous
//
#include <hip/hip_runtime.h>
#include <hip/hip_bf16.h>
#include <math.h>

#define NTOK 65536
#define DIN 256
#define DOUT 256
#define HID 512
#define NEXP 8
#define NBAND 4
#define RANK 8
#define CAP 10240
#define NTILE 64
#define TILES_PER_E (CAP / NTILE)  // 160

// packed bf16 weight region (ushort elements), offsets in elements
#define W1CAT_PER_E (34 * 9 * 512)            // 156672
#define B1CAT_OFF   (NEXP * W1CAT_PER_E)      // 1253376
#define B1CAT_PER_E (32 * 512)                // 16384
#define W2CAT_OFF   (B1CAT_OFF + NEXP * B1CAT_PER_E)  // 1384448
#define W2CAT_PER_E (18 * 16 * 512)           // 147456
#define B2CAT_OFF   (W2CAT_OFF + NEXP * W2CAT_PER_E)  // 2564096
#define B2CAT_PER_E (16 * 512)                // 8192
#define PK_TOTAL    (B2CAT_OFF + NEXP * B2CAT_PER_E)  // 2629632 = 2568*1024
#define PK_F32_OFF  1200000                   // f32-word offset of packed region in ws

typedef short s16x8 __attribute__((ext_vector_type(8)));
typedef float f32x4 __attribute__((ext_vector_type(4)));

__device__ __forceinline__ unsigned key_of(float f) {
    unsigned u = __float_as_uint(f);
    return (u & 0x80000000u) ? ~u : (u | 0x80000000u);
}
// fast tanh-gelu: tanh(z) = 1 - 2/(e^{2z}+1)  ->  gelu(v) = v*(1 - rcp(e^{2z}+1))
__device__ __forceinline__ float gelu_fast(float v) {
    const float c = 0.7978845608028654f;
    float z = c * (v + 0.044715f * v * v * v);
    float e = __expf(2.0f * z);              // inf for large z -> rcp -> 0 (ok)
    return v * (1.0f - __builtin_amdgcn_rcpf(e + 1.0f));
}
__device__ __forceinline__ ushort f2bf(float f) {  // RNE f32->bf16
    unsigned u = __float_as_uint(f);
    return (ushort)((u + 0x7FFFu + ((u >> 16) & 1u)) >> 16);
}

// ---------------- gating GEMV + fused weff-fold + y-zeroing -----------------
// Weff = Wg_x + Wdct @ Wg_f computed per-block into LDS (transposed, padded).
// logits math bit-identical to prior rounds (same FMA order).
__global__ __launch_bounds__(256) void k_logits(const float* __restrict__ x,
                                                const float* __restrict__ Wdct,
                                                const float* __restrict__ Wgate,
                                                float* __restrict__ logitsT,
                                                float* __restrict__ partials,
                                                float* __restrict__ y) {
    __shared__ float wefft[8][257];   // [e][d], padded row
    __shared__ float pr[4][8];
    int tid = threadIdx.x, w = tid >> 6, lane = tid & 63;

    // fold weff: thread d computes row d (same accumulation order as k_foldw)
    {
        int d = tid;
        float acc[8];
#pragma unroll
        for (int e = 0; e < 8; ++e) acc[e] = Wgate[d * 8 + e];
        for (int f = 0; f < 64; ++f) {
            float wv = Wdct[d * 64 + f];
#pragma unroll
            for (int e = 0; e < 8; ++e) acc[e] += wv * Wgate[(256 + f) * 8 + e];
        }
#pragma unroll
        for (int e = 0; e < 8; ++e) wefft[e][d] = acc[e];
    }

    // zero this block's 64 output rows (64 tok x 256 f32 = 4096 float4)
    {
        float4 z = {0.f, 0.f, 0.f, 0.f};
        float4* yp = (float4*)(y + (size_t)blockIdx.x * 64 * DOUT);
        for (int i = tid; i < 4096; i += 256) yp[i] = z;
    }
    __syncthreads();

    // lane-resident Weff rows lane*4..lane*4+3 (scalar LDS reads, 8-way max)
    float wje[4][8];
#pragma unroll
    for (int j = 0; j < 4; ++j)
#pragma unroll
        for (int e = 0; e < 8; ++e) wje[j][e] = wefft[e][lane * 4 + j];

    int wid = blockIdx.x * 4 + w;       // 0..4095
    int nbase = wid * 16;
    float es = 0.f;
    for (int t = 0; t < 16; ++t) {
        int n = nbase + t;
        float4 v = *(const float4*)(x + (size_t)n * DIN + lane * 4);
        float acc[8];
#pragma unroll
        for (int e = 0; e < 8; ++e) acc[e] = 0.f;
#pragma unroll
        for (int j = 0; j < 4; ++j) {
            float vj = (j == 0) ? v.x : (j == 1) ? v.y : (j == 2) ? v.z : v.w;
#pragma unroll
            for (int e = 0; e < 8; ++e) acc[e] += vj * wje[j][e];
        }
#pragma unroll
        for (int off = 1; off < 64; off <<= 1) {
#pragma unroll
            for (int e = 0; e < 8; ++e) acc[e] += __shfl_xor(acc[e], off);
        }
        float out = acc[0];
#pragma unroll
        for (int e = 1; e < 8; ++e) if (lane == e) out = acc[e];
        if (lane < 8) {
            logitsT[(size_t)lane * NTOK + n] = out;
            es += expf(out);
        }
    }
    if (lane < 8) pr[w][lane] = es;
    __syncthreads();
    if (tid < 8) partials[(size_t)tid * 1024 + blockIdx.x] =
        pr[0][tid] + pr[1][tid] + pr[2][tid] + pr[3][tid];
}

// ---------------- fused: top-CAP select (blocks 0..7) || weight pack --------
// Selection: 2 radix passes (16-bit threshold) + 1 select pass (3 scans vs
// the former 5). Ties within the 16-bit threshold bin (~300 expected,
// Binomial sigma~17, 2048 cap = ~100 sigma) ranked by (full key desc, index
// asc) -> selected set identical to the 4-pass radix.
__global__ __launch_bounds__(1024) void k_misc(const float* __restrict__ logitsT,
                                               const float* __restrict__ partials,
                                               float* __restrict__ colsum,
                                               int* __restrict__ idxbuf,
                                               const float* __restrict__ W1,
                                               const float* __restrict__ A1,
                                               const float* __restrict__ B1,
                                               const float* __restrict__ W2,
                                               const float* __restrict__ A2,
                                               const float* __restrict__ B2,
                                               ushort* __restrict__ pk) {
    if (blockIdx.x >= 8) {
        // ---- weight packing branch ----
        int id = (blockIdx.x - 8) * 1024 + threadIdx.x;
        if (id >= PK_TOTAL) return;
        float val;
        if (id < B1CAT_OFF) {
            int e = id / W1CAT_PER_E, rem = id % W1CAT_PER_E;
            int t = rem / (9 * 512); rem %= 9 * 512;
            int s = rem / 512; int q = rem & 511;
            int l = q >> 3, j = q & 7;
            int k = s * 32 + ((l >> 4) << 3) + j;
            int col = t * 16 + (l & 15);
            if (k > 256) val = 0.f;
            else if (col < 512) val = W1[((size_t)e * 257 + k) * 512 + col];
            else {
                int cu = col - 512;
                val = A1[(((size_t)e * NBAND + (cu >> 3)) * 257 + k) * RANK + (cu & 7)];
            }
        } else if (id < W2CAT_OFF) {
            int id2 = id - B1CAT_OFF;
            int e = id2 / B1CAT_PER_E, rem = id2 % B1CAT_PER_E;
            int t = rem / 512; int q = rem & 511;
            int l = q >> 3, j = q & 7;
            int k32 = ((l >> 4) << 3) + j;
            int col = t * 16 + (l & 15);
            val = 2.0f * B1[(((size_t)e * NBAND + (k32 >> 3)) * RANK + (k32 & 7)) * 512 + col];
        } else if (id < B2CAT_OFF) {
            int id2 = id - W2CAT_OFF;
            int e = id2 / W2CAT_PER_E, rem = id2 % W2CAT_PER_E;
            int t = rem / (16 * 512); rem %= 16 * 512;
            int s = rem / 512; int q = rem & 511;
            int l = q >> 3, j = q & 7;
            int k = s * 32 + ((l >> 4) << 3) + j;
            int col = t * 16 + (l & 15);
            if (col < 256) val = W2[((size_t)e * 512 + k) * 256 + col];
            else {
                int cv = col - 256;
                val = A2[(((size_t)e * NBAND + (cv >> 3)) * 512 + k) * RANK + (cv & 7)];
            }
        } else {
            int id2 = id - B2CAT_OFF;
            int e = id2 / B2CAT_PER_E, rem = id2 % B2CAT_PER_E;
            int t = rem / 512; int q = rem & 511;
            int l = q >> 3, j = q & 7;
            int k32 = ((l >> 4) << 3) + j;
            int col = t * 16 + (l & 15);
            val = 2.0f * B2[(((size_t)e * NBAND + (k32 >> 3)) * RANK + (k32 & 7)) * 256 + col];
        }
        pk[id] = f2bf(val);
        return;
    }
    // ---- top-CAP selection branch (one block per expert) ----
    __shared__ unsigned subh[16][257];
    __shared__ unsigned bins[256];
    __shared__ float ssum[16];
    __shared__ unsigned sval[2];   // pref, rem
    __shared__ unsigned scnt, stcnt;
    __shared__ int ties_l[2048];
    __shared__ unsigned ties_k[2048];
    int e = blockIdx.x, tid = threadIdx.x, w = tid >> 6, lane = tid & 63;
    const float* lp = logitsT + (size_t)e * NTOK;

    {
        float s = partials[(size_t)e * 1024 + tid];
#pragma unroll
        for (int off = 32; off > 0; off >>= 1) s += __shfl_xor(s, off);
        if (lane == 0) ssum[w] = s;
        __syncthreads();
        if (tid == 0) {
            float t = 0.f;
#pragma unroll
            for (int i = 0; i < 16; ++i) t += ssum[i];
            colsum[e] = t;
        }
    }
    if (tid == 0) { scnt = 0; stcnt = 0; }

    // 2 radix passes -> exact 16-bit threshold (pref) + within-bin slots (rem)
    unsigned pref = 0, rem = CAP;
    for (int p = 0; p < 2; ++p) {
        int shift = 24 - 8 * p;
        for (int i = tid; i < 16 * 257; i += 1024) ((unsigned*)subh)[i] = 0;
        __syncthreads();
        for (int it = 0; it < 64; ++it) {
            int n = it * 1024 + tid;
            unsigned k = key_of(lp[n]);
            bool ok = (p == 0) || ((k >> (shift + 8)) == pref);
            if (ok) atomicAdd(&subh[w][(k >> shift) & 255u], 1u);
        }
        __syncthreads();
        if (tid < 256) {
            unsigned c = 0;
#pragma unroll
            for (int ww = 0; ww < 16; ++ww) c += subh[ww][tid];
            bins[tid] = c;
        }
        __syncthreads();
        for (int off = 1; off < 256; off <<= 1) {
            unsigned add = (tid < 256 && tid + off < 256) ? bins[tid + off] : 0u;
            __syncthreads();
            if (tid < 256) bins[tid] += add;
            __syncthreads();
        }
        if (tid < 256) {
            unsigned snext = (tid == 255) ? 0u : bins[tid + 1];
            if (bins[tid] >= rem && snext < rem) {
                sval[0] = (pref << 8) | (unsigned)tid;
                sval[1] = rem - snext;
            }
        }
        __syncthreads();
        pref = sval[0];
        rem = sval[1];
        __syncthreads();
    }

    // single select pass on 16-bit keys; ties keyed for exact ranking
    unsigned T = pref;
    for (int it = 0; it < 64; ++it) {
        int n = it * 1024 + tid;
        unsigned k = key_of(lp[n]);
        unsigned k16 = k >> 16;
        if (k16 > T) {
            unsigned pos = atomicAdd(&scnt, 1u);
            idxbuf[e * CAP + pos] = n;
        } else if (k16 == T) {
            unsigned tp = atomicAdd(&stcnt, 1u);
            if (tp < 2048) { ties_l[tp] = n; ties_k[tp] = k; }
        }
    }
    __syncthreads();
    int m = (int)min(stcnt, 2048u), r = (int)rem, base = CAP - r;
    if (m == r) {
        for (int i = tid; i < m; i += 1024) idxbuf[e * CAP + base + i] = ties_l[i];
    } else {
        // rank ties by (full key desc, index asc); r best get slots
        for (int i = tid; i < m; i += 1024) {
            int my = ties_l[i];
            unsigned km = ties_k[i];
            int rank = 0;
            for (int j = 0; j < m; ++j) {
                unsigned kj = ties_k[j];
                rank += (kj > km) || (kj == km && ties_l[j] < my);
            }
            if (rank < r) idxbuf[e * CAP + base + rank] = my;
        }
    }
}

// ---------------- fused expert MLP: block-cooperative LDS staging -----------
// Single-buffer staged W1/W2 (T14 reg-split overlaps load latency with
// compute). No sched pins: compiler inserts fine-grained lgkmcnt itself.
__global__ __launch_bounds__(256, 2) void k_expert(
    const float* __restrict__ x, const int* __restrict__ band,
    const float* __restrict__ b1, const float* __restrict__ b2,
    const ushort* __restrict__ pk,
    const float* __restrict__ logitsT,
    const float* __restrict__ colsum, const int* __restrict__ idxbuf,
    float* __restrict__ y) {
    __shared__ ushort bW1[9216];        // 18 chunks x 512 (tiles 2p,2p+1 x 9 ksteps)
    __shared__ ushort bW2[9216];        // 18 chunks x 512 (t2 0..17, slice p)
    __shared__ ushort sc[4][640];       // per-wave transpose scratch
    __shared__ int s_tok[4][16];
    __shared__ int s_band[4][16];
    __shared__ float s_g[4][16];

    int tid = threadIdx.x, w = tid >> 6, lane = tid & 63;
    int bid = blockIdx.x;
    int e = bid & 7;            // XCD-pinned expert
    int tile = bid >> 3;        // 0..159

    if (lane < 16) {
        int n = idxbuf[e * CAP + tile * NTILE + w * 16 + lane];
        s_tok[w][lane] = n;
        s_band[w][lane] = band[n];
        s_g[w][lane] = expf(logitsT[(size_t)e * NTOK + n]) / colsum[e];
    }

    int l15 = lane & 15, lg = lane >> 4;
    ushort* scw = &sc[w][0];

    // ---- A-frags for layer 1 (K=288: 9 ksteps) ----
    s16x8 a1[9];
    {
        int mytok = s_tok[w][l15];
        const float* xrow = x + (size_t)mytok * DIN;
        int kg = lg << 3;
#pragma unroll
        for (int s = 0; s < 8; ++s) {
            float4 p = *(const float4*)&xrow[s * 32 + kg];
            float4 q = *(const float4*)&xrow[s * 32 + kg + 4];
            s16x8 a;
            a[0] = (short)f2bf(p.x); a[1] = (short)f2bf(p.y);
            a[2] = (short)f2bf(p.z); a[3] = (short)f2bf(p.w);
            a[4] = (short)f2bf(q.x); a[5] = (short)f2bf(q.y);
            a[6] = (short)f2bf(q.z); a[7] = (short)f2bf(q.w);
            a1[s] = a;
        }
        s16x8 a = (s16x8)(short)0;
        if (lane < 16) a[0] = (short)f2bf((float)s_band[w][l15] * 0.25f);
        a1[8] = a;
    }

    const ushort* w1base = pk + (size_t)e * W1CAT_PER_E;
    const ushort* b1base = pk + B1CAT_OFF + (size_t)e * B1CAT_PER_E;
    const ushort* w2base = pk + W2CAT_OFF + (size_t)e * W2CAT_PER_E;
    const ushort* b2base = pk + B2CAT_OFF + (size_t)e * B2CAT_PER_E;

    // ---- issue prologue stage loads (phase 0) into regs ----
    s16x8 stg[9];
    if (w < 2) {
        const ushort* s0 = w2base + (size_t)(w * 9) * 16 * 512 + lane * 8;
#pragma unroll
        for (int i = 0; i < 9; ++i)
            stg[i] = *(const s16x8*)(s0 + (size_t)i * 16 * 512);
    } else {
        const ushort* s0 = w1base + (size_t)(w - 2) * 9 * 512 + lane * 8;
#pragma unroll
        for (int i = 0; i < 9; ++i)
            stg[i] = *(const s16x8*)(s0 + i * 512);
    }

    // ---- LoRA1 u = xe @ A1cat (tiles 32,33, direct global), band-mask ----
    s16x8 ufrag;
    {
#pragma unroll
        for (int t = 32; t <= 33; ++t) {
            f32x4 acc = {0.f, 0.f, 0.f, 0.f};
#pragma unroll
            for (int s = 0; s < 9; ++s) {
                s16x8 b = *(const s16x8*)(w1base + ((size_t)t * 9 + s) * 512 + lane * 8);
                acc = __builtin_amdgcn_mfma_f32_16x16x32_bf16(a1[s], b, acc, 0, 0, 0);
            }
            int colbase = (t - 32) * 16 + l15;
#pragma unroll
            for (int r = 0; r < 4; ++r) {
                int row = lg * 4 + r;
                float v = ((colbase >> 3) == s_band[w][row]) ? acc[r] : 0.f;
                scw[row * 40 + colbase] = f2bf(v);
            }
        }
        ufrag = *(const s16x8*)&scw[l15 * 40 + lg * 8];
    }

    // ---- layer2 accumulators (bias-initialized), LoRA2 accumulators ----
    f32x4 oacc[16];
#pragma unroll
    for (int t2 = 0; t2 < 16; ++t2) {
        float bv = b2[(size_t)e * DOUT + t2 * 16 + l15];
        oacc[t2] = (f32x4){bv, bv, bv, bv};
    }
    f32x4 vacc[2];
    vacc[0] = (f32x4){0.f, 0.f, 0.f, 0.f};
    vacc[1] = (f32x4){0.f, 0.f, 0.f, 0.f};

    // ---- write prologue staged regs to the buffer, sync ----
    if (w < 2) {
#pragma unroll
        for (int i = 0; i < 9; ++i)
            *(s16x8*)(&bW2[(w * 9 + i) * 512] + lane * 8) = stg[i];
    } else {
#pragma unroll
        for (int i = 0; i < 9; ++i)
            *(s16x8*)(&bW1[((w - 2) * 9 + i) * 512] + lane * 8) = stg[i];
    }
    __syncthreads();

#pragma unroll 1
    for (int p = 0; p < 16; ++p) {
        // (a) issue next phase's global loads into regs (land during compute)
        s16x8 st2[9];
        if (p < 15) {
            int p1 = p + 1;
            if (w < 2) {
                const ushort* s0 = w2base + ((size_t)(w * 9) * 16 + p1) * 512 + lane * 8;
#pragma unroll
                for (int i = 0; i < 9; ++i)
                    st2[i] = *(const s16x8*)(s0 + (size_t)i * 16 * 512);
            } else {
                int t = p1 * 2 + (w - 2);
                const ushort* s0 = w1base + (size_t)t * 9 * 512 + lane * 8;
#pragma unroll
                for (int i = 0; i < 9; ++i)
                    st2[i] = *(const s16x8*)(s0 + i * 512);
            }
        }
        // (b) compute phase p from LDS
#pragma unroll
        for (int half = 0; half < 2; ++half) {
            int t = p * 2 + half;
            float bv = b1[(size_t)e * HID + t * 16 + l15];
            f32x4 acc = {bv, bv, bv, bv};
#pragma unroll
            for (int s = 0; s < 9; ++s) {
                s16x8 b = *(const s16x8*)(&bW1[(half * 9 + s) * 512] + lane * 8);
                acc = __builtin_amdgcn_mfma_f32_16x16x32_bf16(a1[s], b, acc, 0, 0, 0);
            }
            {
                s16x8 b = *(const s16x8*)(b1base + (size_t)t * 512 + lane * 8);
                acc = __builtin_amdgcn_mfma_f32_16x16x32_bf16(ufrag, b, acc, 0, 0, 0);
            }
#pragma unroll
            for (int r = 0; r < 4; ++r) {
                int row = lg * 4 + r;
                scw[row * 40 + half * 16 + l15] = f2bf(gelu_fast(acc[r]));
            }
        }
        s16x8 hfrag = *(const s16x8*)&scw[l15 * 40 + lg * 8];
#pragma unroll
        for (int t2 = 0; t2 < 16; ++t2) {
            s16x8 b = *(const s16x8*)(&bW2[t2 * 512] + lane * 8);
            oacc[t2] = __builtin_amdgcn_mfma_f32_16x16x32_bf16(hfrag, b, oacc[t2], 0, 0, 0);
        }
#pragma unroll
        for (int i = 0; i < 2; ++i) {
            s16x8 b = *(const s16x8*)(&bW2[(16 + i) * 512] + lane * 8);
            vacc[i] = __builtin_amdgcn_mfma_f32_16x16x32_bf16(hfrag, b, vacc[i], 0, 0, 0);
        }
        // (c) all waves done READING the buffer -> overwrite with next phase
        if (p < 15) {
            __syncthreads();
            if (w < 2) {
#pragma unroll
                for (int i = 0; i < 9; ++i)
                    *(s16x8*)(&bW2[(w * 9 + i) * 512] + lane * 8) = st2[i];
            } else {
#pragma unroll
                for (int i = 0; i < 9; ++i)
                    *(s16x8*)(&bW1[((w - 2) * 9 + i) * 512] + lane * 8) = st2[i];
            }
            __syncthreads();
        }
    }

    // ---- LoRA2: band-mask v, transpose -> vfrag, fold through B2cat ----
    s16x8 vfrag;
    {
#pragma unroll
        for (int i = 0; i < 2; ++i) {
            int colbase = i * 16 + l15;
#pragma unroll
            for (int r = 0; r < 4; ++r) {
                int row = lg * 4 + r;
                float v = ((colbase >> 3) == s_band[w][row]) ? vacc[i][r] : 0.f;
                scw[row * 40 + colbase] = f2bf(v);
            }
        }
        vfrag = *(const s16x8*)&scw[l15 * 40 + lg * 8];
    }

    float g4[4];
    int tok4[4];
#pragma unroll
    for (int r = 0; r < 4; ++r) {
        int row = lg * 4 + r;
        g4[r] = s_g[w][row];
        tok4[r] = s_tok[w][row];
    }
#pragma unroll
    for (int t2 = 0; t2 < 16; ++t2) {
        s16x8 b = *(const s16x8*)(b2base + (size_t)t2 * 512 + lane * 8);
        f32x4 acc = __builtin_amdgcn_mfma_f32_16x16x32_bf16(vfrag, b, oacc[t2], 0, 0, 0);
        int col = t2 * 16 + l15;
#pragma unroll
        for (int r = 0; r < 4; ++r) {
            atomicAdd(&y[(size_t)tok4[r] * DOUT + col], g4[r] * acc[r]);
        }
    }
}

extern "C" void kernel_launch(void* const* d_in, const int* in_sizes, int n_in,
                              void* d_out, int out_size, void* d_ws, size_t ws_size,
                              hipStream_t stream) {
    const float* x = (const float*)d_in[0];
    const int* band = (const int*)d_in[1];
    const float* Wdct = (const float*)d_in[2];
    const float* Wgate = (const float*)d_in[3];
    const float* W1 = (const float*)d_in[4];
    const float* b1 = (const float*)d_in[5];
    const float* A1 = (const float*)d_in[6];
    const float* B1 = (const float*)d_in[7];
    const float* W2 = (const float*)d_in[8];
    const float* b2 = (const float*)d_in[9];
    const float* A2 = (const float*)d_in[10];
    const float* B2 = (const float*)d_in[11];
    float* y = (float*)d_out;

    float* ws = (float*)d_ws;
    float* logitsT = ws;                          // 524288 words
    float* partials = ws + 524288;                // 8192 (8 experts x 1024 blocks)
    float* colsum = ws + 532480;                  // 8
    int* idxbuf = (int*)(ws + 532488);            // 81920 (ends 614408)
    ushort* pk = (ushort*)(ws + PK_F32_OFF);      // 2629632 bf16 = 5.26 MB

    k_logits<<<1024, 256, 0, stream>>>(x, Wdct, Wgate, logitsT, partials, y);
    k_misc<<<8 + PK_TOTAL / 1024, 1024, 0, stream>>>(logitsT, partials, colsum,
                                                     idxbuf, W1, A1, B1, W2, A2,
                                                     B2, pk);
    k_expert<<<NEXP * TILES_PER_E, 256, 0, stream>>>(x, band, b1, b2, pk,
                                                     logitsT, colsum, idxbuf, y);
}